// Round 3
// baseline (529.086 us; speedup 1.0000x reference)
//
#include <hip/hip_runtime.h>
#include <math.h>

typedef _Float16 f16;
typedef __attribute__((ext_vector_type(8))) _Float16 half8;
typedef __attribute__((ext_vector_type(4))) float f32x4;

#define NEXP 64
#define TM 64
#define L_STRIDE 132

__device__ __forceinline__ float softplus_f(float x) {
    return fmaxf(x, 0.0f) + log1pf(expf(-fabsf(x)));
}

__device__ __forceinline__ void cvt_split(const float4 a, const float4 b,
                                          half8& hv, half8& lv) {
    const float vv[8] = {a.x, a.y, a.z, a.w, b.x, b.y, b.z, b.w};
#pragma unroll
    for (int j = 0; j < 8; ++j) {
        const f16 h = (f16)vv[j];
        hv[j] = h;
        lv[j] = (f16)((vv[j] - (float)h) * 4096.0f);
    }
}

// ---------------- pre-kernel: split W (route|noise) into f16 hi/lo planes ----
// ws layout (f16 units): [kc][plane(2)][q(4)][col(128)][8]   (16 KB per kc)
__global__ void wsplit_kernel(const float* __restrict__ Wr,
                              const float* __restrict__ Wn,
                              f16* __restrict__ ws, int D) {
    const int per_col = D >> 3;
    const int t = blockIdx.x * blockDim.x + threadIdx.x;
    const int col = t / per_col;
    const int k0  = (t - col * per_col) * 8;
    if (col >= 128) return;
    const float* src = (col < NEXP) ? &Wr[(size_t)col * D] : &Wn[(size_t)(col - NEXP) * D];
    const float4 v0 = *(const float4*)&src[k0];
    const float4 v1 = *(const float4*)&src[k0 + 4];
    half8 hi, lo;
    cvt_split(v0, v1, hi, lo);
    const int kc = k0 >> 5, q = (k0 >> 3) & 3;
    const size_t base = (size_t)kc * 8192 + (size_t)q * 1024 + (size_t)col * 8;
    *(half8*)&ws[base]        = hi;
    *(half8*)&ws[base + 4096] = lo;
}

// ---------------- main kernel: barrier-free direct-to-register MFMA GEMM -----
// B (2 MB total) is L2-resident: loading fragments straight from global costs
// the same L2 traffic as LDS staging but deletes the DMA + barrier + ds_read
// structure that measured 75% idle (m233-style 2-phase stall). Waves are fully
// independent in the K-loop: global->reg loads, in-register cvt, MFMA.
// Pipeline: A (x, HBM) prefetched at distance 2; B (ws, L2-hot) at distance 1,
// via a manual 2-body unroll with named register sets (no copies, no dynamic
// indexing -> everything stays in VGPRs).
__global__ __launch_bounds__(256, 2)
void router_mfma_kernel(const float* __restrict__ x,
                        const f16* __restrict__ wsW,
                        const float* __restrict__ br,
                        const float* __restrict__ bn,
                        const float* __restrict__ eps,
                        float* __restrict__ out,
                        int N, int D) {
    __shared__ float L[TM][L_STRIDE];     // 33.8 KB logits scratch
    __shared__ float biasLDS[128];
    __shared__ float p1s[TM], p2s[TM];
    __shared__ int   i1s[TM], i2s[TM];

    const int tid  = threadIdx.x;
    const int lane = tid & 63;
    const int w    = tid >> 6;
    const int rowbase = blockIdx.x * TM;
    const int wr = w & 1, wc = w >> 1;     // wave tile: 32 rows x 64 cols
    const int quad = lane >> 4;
    const int l16  = lane & 15;

    if (tid < 128) biasLDS[tid] = (tid < NEXP) ? br[tid] : bn[tid - NEXP];

    f32x4 accM[2][4], accC[2][4];
#pragma unroll
    for (int i = 0; i < 2; ++i)
#pragma unroll
        for (int j = 0; j < 4; ++j) {
            accM[i][j] = (f32x4){0.f, 0.f, 0.f, 0.f};
            accC[i][j] = (f32x4){0.f, 0.f, 0.f, 0.f};
        }

    // A source: lane (quad,l16) of wave-row-half wr reads rows wr*32+l16 and
    // wr*32+16+l16, k-slice quad*8..quad*8+7 of each 32-wide chunk.
    const float* xA0 = x + (size_t)(rowbase + wr * 32 + l16) * D + quad * 8;
    const float* xA1 = xA0 + (size_t)16 * D;
    // B source: f16 units. col = wc*64 + ct*16 + l16; addr = kc*8192 +
    // plane*4096 + quad*1024 + col*8  ->  base + kc*8192 + ct*128 (+4096 lo).
    const f16* bsrc = wsW + quad * 1024 + (size_t)(wc * 64 + l16) * 8;

    const int nkc = D >> 5;   // 64 (even; host guards D==2048)

    // ---- prologue: A chunks 0,1 ; B chunk 0
    float4 aE00 = *(const float4*)&xA0[0];
    float4 aE01 = *(const float4*)&xA0[4];
    float4 aE10 = *(const float4*)&xA1[0];
    float4 aE11 = *(const float4*)&xA1[4];
    float4 aO00 = *(const float4*)&xA0[32];
    float4 aO01 = *(const float4*)&xA0[36];
    float4 aO10 = *(const float4*)&xA1[32];
    float4 aO11 = *(const float4*)&xA1[36];
    half8 bhE0 = *(const half8*)&bsrc[0];
    half8 bhE1 = *(const half8*)&bsrc[128];
    half8 bhE2 = *(const half8*)&bsrc[256];
    half8 bhE3 = *(const half8*)&bsrc[384];
    half8 blE0 = *(const half8*)&bsrc[4096];
    half8 blE1 = *(const half8*)&bsrc[4224];
    half8 blE2 = *(const half8*)&bsrc[4352];
    half8 blE3 = *(const half8*)&bsrc[4480];
    half8 bhO0, bhO1, bhO2, bhO3, blO0, blO1, blO2, blO3;

#define MFMA_BLOCK(AH0, AL0, AH1, AL1, BH0, BH1, BH2, BH3, BL0, BL1, BL2, BL3) \
    {                                                                          \
        half8 ah[2], al[2], bh[4], bl[4];                                      \
        ah[0] = AH0; al[0] = AL0; ah[1] = AH1; al[1] = AL1;                    \
        bh[0] = BH0; bh[1] = BH1; bh[2] = BH2; bh[3] = BH3;                    \
        bl[0] = BL0; bl[1] = BL1; bl[2] = BL2; bl[3] = BL3;                    \
        _Pragma("unroll")                                                      \
        for (int rt = 0; rt < 2; ++rt)                                         \
            _Pragma("unroll")                                                  \
            for (int ct = 0; ct < 4; ++ct) {                                   \
                accM[rt][ct] = __builtin_amdgcn_mfma_f32_16x16x32_f16(         \
                    ah[rt], bh[ct], accM[rt][ct], 0, 0, 0);                    \
                accC[rt][ct] = __builtin_amdgcn_mfma_f32_16x16x32_f16(         \
                    al[rt], bh[ct], accC[rt][ct], 0, 0, 0);                    \
                accC[rt][ct] = __builtin_amdgcn_mfma_f32_16x16x32_f16(         \
                    ah[rt], bl[ct], accC[rt][ct], 0, 0, 0);                    \
            }                                                                  \
    }

    for (int kc = 0; kc < nkc; kc += 2) {
        // ================= body even (uses aE / bE, chunk kc) ================
        {
            const int ia = (kc + 2 < nkc) ? (kc + 2) : (nkc - 1);   // A dist 2
            const int ib = (kc + 1 < nkc) ? (kc + 1) : (nkc - 1);   // B dist 1
            // issue next loads first (independent of current frags)
            const f16* bp = bsrc + (size_t)ib * 8192;
            bhO0 = *(const half8*)&bp[0];
            bhO1 = *(const half8*)&bp[128];
            bhO2 = *(const half8*)&bp[256];
            bhO3 = *(const half8*)&bp[384];
            blO0 = *(const half8*)&bp[4096];
            blO1 = *(const half8*)&bp[4224];
            blO2 = *(const half8*)&bp[4352];
            blO3 = *(const half8*)&bp[4480];
            const float* p0 = xA0 + ia * 32;
            const float* p1 = xA1 + ia * 32;
            // current frags from aE (loaded 2 bodies ago)
            half8 ah0, al0, ah1, al1;
            cvt_split(aE00, aE01, ah0, al0);
            cvt_split(aE10, aE11, ah1, al1);
            aE00 = *(const float4*)&p0[0];
            aE01 = *(const float4*)&p0[4];
            aE10 = *(const float4*)&p1[0];
            aE11 = *(const float4*)&p1[4];
            MFMA_BLOCK(ah0, al0, ah1, al1, bhE0, bhE1, bhE2, bhE3,
                       blE0, blE1, blE2, blE3)
        }
        // ================= body odd (uses aO / bO, chunk kc+1) ===============
        {
            const int ia = (kc + 3 < nkc) ? (kc + 3) : (nkc - 1);   // A dist 2
            const int ib = (kc + 2 < nkc) ? (kc + 2) : (nkc - 1);   // B dist 1
            const f16* bp = bsrc + (size_t)ib * 8192;
            bhE0 = *(const half8*)&bp[0];
            bhE1 = *(const half8*)&bp[128];
            bhE2 = *(const half8*)&bp[256];
            bhE3 = *(const half8*)&bp[384];
            blE0 = *(const half8*)&bp[4096];
            blE1 = *(const half8*)&bp[4224];
            blE2 = *(const half8*)&bp[4352];
            blE3 = *(const half8*)&bp[4480];
            const float* p0 = xA0 + ia * 32;
            const float* p1 = xA1 + ia * 32;
            half8 ah0, al0, ah1, al1;
            cvt_split(aO00, aO01, ah0, al0);
            cvt_split(aO10, aO11, ah1, al1);
            aO00 = *(const float4*)&p0[0];
            aO01 = *(const float4*)&p0[4];
            aO10 = *(const float4*)&p1[0];
            aO11 = *(const float4*)&p1[4];
            MFMA_BLOCK(ah0, al0, ah1, al1, bhO0, bhO1, bhO2, bhO3,
                       blO0, blO1, blO2, blO3)
        }
    }
#undef MFMA_BLOCK

    // ---- combine accs + bias -> logits in LDS (C/D: col=lane&15, row=quad*4+reg)
#pragma unroll
    for (int rt = 0; rt < 2; ++rt)
#pragma unroll
        for (int ct = 0; ct < 4; ++ct) {
            const int row = wr * 32 + rt * 16 + quad * 4;
            const int col = wc * 64 + ct * 16 + l16;
            const float bcol = biasLDS[col];
#pragma unroll
            for (int rg = 0; rg < 4; ++rg)
                L[row + rg][col] = accM[rt][ct][rg] + accC[rt][ct][rg] * (1.0f / 4096.0f) + bcol;
        }
    __syncthreads();

    // ---- noisy logits in-place over cols 0..63
#pragma unroll
    for (int t = 0; t < 4; ++t) {
        const int f   = tid * 4 + t * 1024;
        const int row = f >> 6;
        const int e0  = f & 63;
        const float4 ev = *(const float4*)&eps[(size_t)(rowbase + row) * NEXP + e0];
        const float evs[4] = {ev.x, ev.y, ev.z, ev.w};
#pragma unroll
        for (int j = 0; j < 4; ++j) {
            const float lg = L[row][e0 + j];
            const float nz = L[row][NEXP + e0 + j];
            L[row][e0 + j] = fmaf(evs[j], softplus_f(nz), lg);
        }
    }
    __syncthreads();

    // ---- per-row top-2 (strict > = first-occurrence tie-break, matches top_k)
    if (tid < TM) {
        const int r = tid;
        float v1t = -INFINITY, v2t = -INFINITY;
        int i1 = 0, i2 = 0;
#pragma unroll 8
        for (int e = 0; e < NEXP; ++e) {
            const float v = L[r][e];
            if (v > v1t) { v2t = v1t; i2 = i1; v1t = v; i1 = e; }
            else if (v > v2t) { v2t = v; i2 = e; }
        }
        const float z = expf(v2t - v1t);
        const float s = 1.0f + z;
        p1s[r] = 1.0f / s;
        p2s[r] = z / s;
        i1s[r] = i1;
        i2s[r] = i2;
        float* oidx = out + (size_t)N * NEXP + (size_t)(rowbase + r) * 2;
        oidx[0] = (float)i1;
        oidx[1] = (float)i2;
    }
    __syncthreads();

    // ---- sparse-softmax rows, coalesced
    {
        const int r = tid >> 2;
        const int g = tid & 3;
        const float pa = p1s[r], pb = p2s[r];
        const int i1 = i1s[r], i2 = i2s[r];
        float* orow = out + (size_t)(rowbase + r) * NEXP;
#pragma unroll
        for (int t = 0; t < 4; ++t) {
            const int e0 = g * 16 + t * 4;
            float4 o;
            o.x = (e0 + 0 == i1) ? pa : ((e0 + 0 == i2) ? pb : 0.0f);
            o.y = (e0 + 1 == i1) ? pa : ((e0 + 1 == i2) ? pb : 0.0f);
            o.z = (e0 + 2 == i1) ? pa : ((e0 + 2 == i2) ? pb : 0.0f);
            o.w = (e0 + 3 == i1) ? pa : ((e0 + 3 == i2) ? pb : 0.0f);
            *(float4*)&orow[e0] = o;
        }
    }
}

// ---------------- fallback: verified fp32 kernel from R1 ---------------------
#define BK 32
#define XS_STRIDE (TM + 4)
#define WS_STRIDE (128 + 4)

__global__ __launch_bounds__(256, 2)
void noisy_topk_router_kernel(const float* __restrict__ x,
                              const float* __restrict__ Wr,
                              const float* __restrict__ br,
                              const float* __restrict__ Wn,
                              const float* __restrict__ bn,
                              const float* __restrict__ eps,
                              float* __restrict__ out,
                              int N, int D) {
    __shared__ union alignas(16) {
        struct {
            float Xs[BK][XS_STRIDE];
            float Ws[BK][WS_STRIDE];
        } st;
        float L[TM][L_STRIDE];
    } sm;
    __shared__ float p1s[TM], p2s[TM];
    __shared__ int   i1s[TM], i2s[TM];

    const int tid = threadIdx.x;
    const int rowbase = blockIdx.x * TM;
    const int r0 = (tid >> 5) * 8;
    const int c0 = (tid & 31) * 4;

    float acc[8][4];
#pragma unroll
    for (int i = 0; i < 8; ++i)
#pragma unroll
        for (int j = 0; j < 4; ++j) acc[i][j] = 0.0f;

    const int q  = tid & 7;
    const int rr = tid >> 3;

    for (int k0 = 0; k0 < D; k0 += BK) {
#pragma unroll
        for (int i = 0; i < 2; ++i) {
            const int row = rr + 32 * i;
            const float4 xv = *(const float4*)&x[(size_t)(rowbase + row) * D + k0 + q * 4];
            sm.st.Xs[q * 4 + 0][row] = xv.x;
            sm.st.Xs[q * 4 + 1][row] = xv.y;
            sm.st.Xs[q * 4 + 2][row] = xv.z;
            sm.st.Xs[q * 4 + 3][row] = xv.w;
            const float4 wv = *(const float4*)&Wr[(size_t)row * D + k0 + q * 4];
            sm.st.Ws[q * 4 + 0][row] = wv.x;
            sm.st.Ws[q * 4 + 1][row] = wv.y;
            sm.st.Ws[q * 4 + 2][row] = wv.z;
            sm.st.Ws[q * 4 + 3][row] = wv.w;
            const float4 nv = *(const float4*)&Wn[(size_t)row * D + k0 + q * 4];
            sm.st.Ws[q * 4 + 0][NEXP + row] = nv.x;
            sm.st.Ws[q * 4 + 1][NEXP + row] = nv.y;
            sm.st.Ws[q * 4 + 2][NEXP + row] = nv.z;
            sm.st.Ws[q * 4 + 3][NEXP + row] = nv.w;
        }
        __syncthreads();
#pragma unroll 4
        for (int kk = 0; kk < BK; ++kk) {
            const float4 xa = *(const float4*)&sm.st.Xs[kk][r0];
            const float4 xb = *(const float4*)&sm.st.Xs[kk][r0 + 4];
            const float4 wv = *(const float4*)&sm.st.Ws[kk][c0];
            const float xs[8] = {xa.x, xa.y, xa.z, xa.w, xb.x, xb.y, xb.z, xb.w};
            const float ws[4] = {wv.x, wv.y, wv.z, wv.w};
#pragma unroll
            for (int i = 0; i < 8; ++i)
#pragma unroll
                for (int j = 0; j < 4; ++j)
                    acc[i][j] = fmaf(xs[i], ws[j], acc[i][j]);
        }
        __syncthreads();
    }
    {
        const float4 bv = (c0 < NEXP) ? *(const float4*)&br[c0]
                                      : *(const float4*)&bn[c0 - NEXP];
#pragma unroll
        for (int i = 0; i < 8; ++i) {
            float4 o;
            o.x = acc[i][0] + bv.x;
            o.y = acc[i][1] + bv.y;
            o.z = acc[i][2] + bv.z;
            o.w = acc[i][3] + bv.w;
            *(float4*)&sm.L[r0 + i][c0] = o;
        }
    }
    __syncthreads();
#pragma unroll
    for (int t = 0; t < 4; ++t) {
        const int f   = tid * 4 + t * 1024;
        const int row = f >> 6;
        const int e0  = f & 63;
        const float4 ev = *(const float4*)&eps[(size_t)(rowbase + row) * NEXP + e0];
        const float evs[4] = {ev.x, ev.y, ev.z, ev.w};
#pragma unroll
        for (int j = 0; j < 4; ++j) {
            const float lg = sm.L[row][e0 + j];
            const float nz = sm.L[row][NEXP + e0 + j];
            sm.L[row][e0 + j] = fmaf(evs[j], softplus_f(nz), lg);
        }
    }
    __syncthreads();
    if (tid < TM) {
        const int r = tid;
        float v1 = -INFINITY, v2 = -INFINITY;
        int i1 = 0, i2 = 0;
#pragma unroll 8
        for (int e = 0; e < NEXP; ++e) {
            const float v = sm.L[r][e];
            if (v > v1) { v2 = v1; i2 = i1; v1 = v; i1 = e; }
            else if (v > v2) { v2 = v; i2 = e; }
        }
        const float z = expf(v2 - v1);
        const float s = 1.0f + z;
        p1s[r] = 1.0f / s;
        p2s[r] = z / s;
        i1s[r] = i1;
        i2s[r] = i2;
        float* oidx = out + (size_t)N * NEXP + (size_t)(rowbase + r) * 2;
        oidx[0] = (float)i1;
        oidx[1] = (float)i2;
    }
    __syncthreads();
    {
        const int r = tid >> 2;
        const int g = tid & 3;
        const float pa = p1s[r], pb = p2s[r];
        const int i1 = i1s[r], i2 = i2s[r];
        float* orow = out + (size_t)(rowbase + r) * NEXP;
#pragma unroll
        for (int t = 0; t < 4; ++t) {
            const int e0 = g * 16 + t * 4;
            float4 o;
            o.x = (e0 + 0 == i1) ? pa : ((e0 + 0 == i2) ? pb : 0.0f);
            o.y = (e0 + 1 == i1) ? pa : ((e0 + 1 == i2) ? pb : 0.0f);
            o.z = (e0 + 2 == i1) ? pa : ((e0 + 2 == i2) ? pb : 0.0f);
            o.w = (e0 + 3 == i1) ? pa : ((e0 + 3 == i2) ? pb : 0.0f);
            *(float4*)&orow[e0] = o;
        }
    }
}

extern "C" void kernel_launch(void* const* d_in, const int* in_sizes, int n_in,
                              void* d_out, int out_size, void* d_ws, size_t ws_size,
                              hipStream_t stream) {
    const float* x   = (const float*)d_in[0];
    const float* Wr  = (const float*)d_in[1];
    const float* br  = (const float*)d_in[2];
    const float* Wn  = (const float*)d_in[3];
    const float* bn  = (const float*)d_in[4];
    const float* eps = (const float*)d_in[5];
    float* out = (float*)d_out;

    const int E = in_sizes[2];
    const int D = in_sizes[1] / E;
    const int N = in_sizes[0] / D;

    const size_t ws_needed = (size_t)128 * D * 2 * sizeof(f16);
    const bool fast = (E == 64) && (D == 2048) && (N % TM == 0) && (ws_size >= ws_needed);

    if (fast) {
        const int pre_threads = 128 * (D / 8);
        wsplit_kernel<<<(pre_threads + 255) / 256, 256, 0, stream>>>(Wr, Wn, (f16*)d_ws, D);
        router_mfma_kernel<<<N / TM, 256, 0, stream>>>(x, (const f16*)d_ws, br, bn, eps, out, N, D);
    } else {
        noisy_topk_router_kernel<<<N / TM, 256, 0, stream>>>(x, Wr, br, Wn, bn, eps, out, N, D);
    }
}

// Round 4
// 433.480 us; speedup vs baseline: 1.2206x; 1.2206x over previous
//
#include <hip/hip_runtime.h>
#include <math.h>

typedef _Float16 f16;
typedef __attribute__((ext_vector_type(8))) _Float16 half8;
typedef __attribute__((ext_vector_type(4))) float f32x4;

#define NEXP 64
#define TMR 32          // fast-kernel rows per block (grid 1024 -> 4 blocks/CU)
#define TM 64           // fallback rows per block
#define L_STRIDE 132

__device__ __forceinline__ float softplus_f(float x) {
    return fmaxf(x, 0.0f) + log1pf(expf(-fabsf(x)));
}

__device__ __forceinline__ void lds_dma16(const void* g, void* l) {
    __builtin_amdgcn_global_load_lds(
        (const __attribute__((address_space(1))) unsigned int*)g,
        (__attribute__((address_space(3))) unsigned int*)l, 16, 0, 0);
}

__device__ __forceinline__ void cvt_split(const float4 a, const float4 b,
                                          half8& hv, half8& lv) {
    const float vv[8] = {a.x, a.y, a.z, a.w, b.x, b.y, b.z, b.w};
#pragma unroll
    for (int j = 0; j < 8; ++j) {
        const f16 h = (f16)vv[j];
        hv[j] = h;
        lv[j] = (f16)((vv[j] - (float)h) * 4096.0f);
    }
}

// ---------------- pre-kernel: split W (route|noise) into f16 hi/lo planes ----
// ws layout (f16 units): [kc][plane(2)][q(4)][col(128)][8]   (16 KB per kc)
__global__ void wsplit_kernel(const float* __restrict__ Wr,
                              const float* __restrict__ Wn,
                              f16* __restrict__ ws, int D) {
    const int per_col = D >> 3;
    const int t = blockIdx.x * blockDim.x + threadIdx.x;
    const int col = t / per_col;
    const int k0  = (t - col * per_col) * 8;
    if (col >= 128) return;
    const float* src = (col < NEXP) ? &Wr[(size_t)col * D] : &Wn[(size_t)(col - NEXP) * D];
    const float4 v0 = *(const float4*)&src[k0];
    const float4 v1 = *(const float4*)&src[k0 + 4];
    half8 hi, lo;
    cvt_split(v0, v1, hi, lo);
    const int kc = k0 >> 5, q = (k0 >> 3) & 3;
    const size_t base = (size_t)kc * 8192 + (size_t)q * 1024 + (size_t)col * 8;
    *(half8*)&ws[base]        = hi;
    *(half8*)&ws[base + 4096] = lo;
}

// ---------------- main kernel: TMR=32, 4 blocks/CU, B-staged / A-direct ------
// Mechanism: the 2-phase barrier structure idles ~75% per barrier-group; with
// grid=512 we were capped at 2 blocks/CU. TMR=32 doubles the grid -> 4
// independent barrier groups per CU (16 waves) so other blocks' waves cover
// each block's barrier drain (m114 overlap). LDS cut to 32 KB (B dbuf only):
// A goes global->reg->cvt per wave (no A staging, no lgkm dep for A), bias
// read from global in the epilogue. Counted vmcnt keeps the distance-2 A
// register prefetch in flight across barriers; sched_barrier(0) fences pin
// the issue order (round-3 lesson: without fences the compiler re-sinks the
// loads and the pipeline evaporates).
__global__ __launch_bounds__(256, 4)
void router_mfma_kernel(const float* __restrict__ x,
                        const f16* __restrict__ wsW,
                        const float* __restrict__ br,
                        const float* __restrict__ bn,
                        const float* __restrict__ eps,
                        float* __restrict__ out,
                        int N, int D) {
    // B dbuf: [buf][plane][q][col][8] f16 = 16 KB/buf = 32 KB total.
    __shared__ union alignas(16) {
        f16 B[2][8192];                                   // 32 KB
        struct {
            float L[TMR][L_STRIDE];                       // 16.9 KB
            float p1[TMR], p2[TMR];
            int   i1[TMR], i2[TMR];
        } ep;
    } sm;

    const int tid  = threadIdx.x;
    const int lane = tid & 63;
    const int w    = tid >> 6;
    const int rowbase = blockIdx.x * TMR;
    const int wr = w & 1, wc = w >> 1;     // wave tile: 16 rows x 64 cols
    const int quad = lane >> 4;
    const int l16  = lane & 15;

    f32x4 accM[4], accC[4];
#pragma unroll
    for (int j = 0; j < 4; ++j) {
        accM[j] = (f32x4){0.f, 0.f, 0.f, 0.f};
        accC[j] = (f32x4){0.f, 0.f, 0.f, 0.f};
    }

    // A-direct: lane (quad,l16) owns row rowbase + wr*16 + l16, k-slice quad*8.
    const float* xA = x + (size_t)(rowbase + wr * 16 + l16) * D + quad * 8;
    const int nkc = D >> 5;   // 64 (even; host guards D==2048)

    // Two A register sets: aE holds even chunks, aO odd chunks (parity by
    // manual unroll-2 so indexing is compile-time, rule #20).
    float4 aE0, aE1, aO0, aO1;

    // ---- prologue: DMA B[0] (oldest in queue), then A(0),A(1) reg loads
    {
        const char* gsrc = (const char*)wsW + w * 4096 + lane * 16;
        char* ldst = (char*)&sm.B[0][0] + w * 4096;
#pragma unroll
        for (int i = 0; i < 4; ++i) lds_dma16(gsrc + i * 1024, ldst + i * 1024);
        __builtin_amdgcn_sched_barrier(0);
        aE0 = *(const float4*)&xA[0];       // chunk 0
        aE1 = *(const float4*)&xA[4];
        aO0 = *(const float4*)&xA[32];      // chunk 1
        aO1 = *(const float4*)&xA[36];
        __builtin_amdgcn_sched_barrier(0);
        // retire the 4 DMAs (oldest), keep the 4 A loads in flight
        asm volatile("s_waitcnt vmcnt(4)" : : : "memory");
        __builtin_amdgcn_s_barrier();
        __builtin_amdgcn_sched_barrier(0);
    }

    // Per body: issue DMA(kc+1) -> cvt A(kc) -> reload A(kc+2) into same set
    // -> B frag ds_reads -> 12 MFMA -> counted wait -> barrier.
    // Steady-state queue at end wait: {A(kc+1)[2], DMA(kc+1)[4], A(kc+2)[2]}
    // -> vmcnt(2) retires DMA + A(kc+1), keeps A(kc+2) in flight.
#define KLOOP_BODY(KC, A0, A1)                                                 \
    {                                                                          \
        const int cur = (KC) & 1, nxt = cur ^ 1;                               \
        if ((KC) + 1 < nkc) {                                                  \
            const char* gsrc = (const char*)wsW + (size_t)((KC) + 1) * 16384   \
                               + w * 4096 + lane * 16;                         \
            char* ldst = (char*)&sm.B[nxt][0] + w * 4096;                      \
            lds_dma16(gsrc,        ldst);                                      \
            lds_dma16(gsrc + 1024, ldst + 1024);                               \
            lds_dma16(gsrc + 2048, ldst + 2048);                               \
            lds_dma16(gsrc + 3072, ldst + 3072);                               \
        }                                                                      \
        __builtin_amdgcn_sched_barrier(0);                                     \
        half8 ah, al;                                                          \
        cvt_split(A0, A1, ah, al);                                             \
        if ((KC) + 2 < nkc) {                                                  \
            A0 = *(const float4*)&xA[((KC) + 2) * 32];                         \
            A1 = *(const float4*)&xA[((KC) + 2) * 32 + 4];                     \
        }                                                                      \
        __builtin_amdgcn_sched_barrier(0);                                     \
        half8 bh[4], bl[4];                                                    \
        _Pragma("unroll")                                                      \
        for (int ct = 0; ct < 4; ++ct) {                                       \
            const int c = (wc * 64 + ct * 16 + l16) * 8;                       \
            bh[ct] = *(const half8*)&sm.B[cur][quad * 1024 + c];               \
            bl[ct] = *(const half8*)&sm.B[cur][4096 + quad * 1024 + c];        \
        }                                                                      \
        _Pragma("unroll")                                                      \
        for (int ct = 0; ct < 4; ++ct) {                                       \
            accM[ct] = __builtin_amdgcn_mfma_f32_16x16x32_f16(                 \
                ah, bh[ct], accM[ct], 0, 0, 0);                                \
            accC[ct] = __builtin_amdgcn_mfma_f32_16x16x32_f16(                 \
                al, bh[ct], accC[ct], 0, 0, 0);                                \
            accC[ct] = __builtin_amdgcn_mfma_f32_16x16x32_f16(                 \
                ah, bl[ct], accC[ct], 0, 0, 0);                                \
        }                                                                      \
        if ((KC) + 2 < nkc)                                                    \
            asm volatile("s_waitcnt vmcnt(2) lgkmcnt(0)" : : : "memory");      \
        else                                                                   \
            asm volatile("s_waitcnt vmcnt(0) lgkmcnt(0)" : : : "memory");      \
        __builtin_amdgcn_s_barrier();                                          \
        __builtin_amdgcn_sched_barrier(0);                                     \
    }

    for (int kc = 0; kc < nkc; kc += 2) {
        KLOOP_BODY(kc,     aE0, aE1)
        KLOOP_BODY(kc + 1, aO0, aO1)
    }
#undef KLOOP_BODY

    // ---- combine accs + bias -> logits in LDS (C/D: col=lane&15, row=quad*4+rg)
    // bias pointer is wave-uniform (wc selects route vs noise plane).
    {
        const float* bias = wc ? bn : br;
        const int row = wr * 16 + quad * 4;
#pragma unroll
        for (int ct = 0; ct < 4; ++ct) {
            const int col = wc * 64 + ct * 16 + l16;
            const float bcol = bias[ct * 16 + l16];
#pragma unroll
            for (int rg = 0; rg < 4; ++rg)
                sm.ep.L[row + rg][col] =
                    accM[ct][rg] + accC[ct][rg] * (1.0f / 4096.0f) + bcol;
        }
    }
    __syncthreads();

    // ---- noisy logits in-place over cols 0..63 (32 rows x 64 cols = 2048)
#pragma unroll
    for (int t = 0; t < 2; ++t) {
        const int f   = tid * 4 + t * 1024;
        const int row = f >> 6;
        const int e0  = f & 63;
        const float4 ev = *(const float4*)&eps[(size_t)(rowbase + row) * NEXP + e0];
        const float evs[4] = {ev.x, ev.y, ev.z, ev.w};
#pragma unroll
        for (int j = 0; j < 4; ++j) {
            const float lg = sm.ep.L[row][e0 + j];
            const float nz = sm.ep.L[row][NEXP + e0 + j];
            sm.ep.L[row][e0 + j] = fmaf(evs[j], softplus_f(nz), lg);
        }
    }
    __syncthreads();

    // ---- per-row top-2 (strict > = first-occurrence tie-break, matches top_k)
    if (tid < TMR) {
        const int r = tid;
        float v1t = -INFINITY, v2t = -INFINITY;
        int i1 = 0, i2 = 0;
#pragma unroll 8
        for (int e = 0; e < NEXP; ++e) {
            const float v = sm.ep.L[r][e];
            if (v > v1t) { v2t = v1t; i2 = i1; v1t = v; i1 = e; }
            else if (v > v2t) { v2t = v; i2 = e; }
        }
        const float z = expf(v2t - v1t);
        const float s = 1.0f + z;
        sm.ep.p1[r] = 1.0f / s;
        sm.ep.p2[r] = z / s;
        sm.ep.i1[r] = i1;
        sm.ep.i2[r] = i2;
        float* oidx = out + (size_t)N * NEXP + (size_t)(rowbase + r) * 2;
        oidx[0] = (float)i1;
        oidx[1] = (float)i2;
    }
    __syncthreads();

    // ---- sparse-softmax rows, coalesced (8 threads per row, 8 cols each)
    {
        const int r = tid >> 3;
        const int g = tid & 7;
        const float pa = sm.ep.p1[r], pb = sm.ep.p2[r];
        const int i1 = sm.ep.i1[r], i2 = sm.ep.i2[r];
        float* orow = out + (size_t)(rowbase + r) * NEXP;
#pragma unroll
        for (int t = 0; t < 2; ++t) {
            const int e0 = g * 8 + t * 4;
            float4 o;
            o.x = (e0 + 0 == i1) ? pa : ((e0 + 0 == i2) ? pb : 0.0f);
            o.y = (e0 + 1 == i1) ? pa : ((e0 + 1 == i2) ? pb : 0.0f);
            o.z = (e0 + 2 == i1) ? pa : ((e0 + 2 == i2) ? pb : 0.0f);
            o.w = (e0 + 3 == i1) ? pa : ((e0 + 3 == i2) ? pb : 0.0f);
            *(float4*)&orow[e0] = o;
        }
    }
}

// ---------------- fallback: verified fp32 kernel from R1 (TM=64) ------------
#define BK 32
#define XS_STRIDE (TM + 4)
#define WS_STRIDE (128 + 4)

__global__ __launch_bounds__(256, 2)
void noisy_topk_router_kernel(const float* __restrict__ x,
                              const float* __restrict__ Wr,
                              const float* __restrict__ br,
                              const float* __restrict__ Wn,
                              const float* __restrict__ bn,
                              const float* __restrict__ eps,
                              float* __restrict__ out,
                              int N, int D) {
    __shared__ union alignas(16) {
        struct {
            float Xs[BK][XS_STRIDE];
            float Ws[BK][WS_STRIDE];
        } st;
        float L[TM][L_STRIDE];
    } sm;
    __shared__ float p1s[TM], p2s[TM];
    __shared__ int   i1s[TM], i2s[TM];

    const int tid = threadIdx.x;
    const int rowbase = blockIdx.x * TM;
    const int r0 = (tid >> 5) * 8;
    const int c0 = (tid & 31) * 4;

    float acc[8][4];
#pragma unroll
    for (int i = 0; i < 8; ++i)
#pragma unroll
        for (int j = 0; j < 4; ++j) acc[i][j] = 0.0f;

    const int q  = tid & 7;
    const int rr = tid >> 3;

    for (int k0 = 0; k0 < D; k0 += BK) {
#pragma unroll
        for (int i = 0; i < 2; ++i) {
            const int row = rr + 32 * i;
            const float4 xv = *(const float4*)&x[(size_t)(rowbase + row) * D + k0 + q * 4];
            sm.st.Xs[q * 4 + 0][row] = xv.x;
            sm.st.Xs[q * 4 + 1][row] = xv.y;
            sm.st.Xs[q * 4 + 2][row] = xv.z;
            sm.st.Xs[q * 4 + 3][row] = xv.w;
            const float4 wv = *(const float4*)&Wr[(size_t)row * D + k0 + q * 4];
            sm.st.Ws[q * 4 + 0][row] = wv.x;
            sm.st.Ws[q * 4 + 1][row] = wv.y;
            sm.st.Ws[q * 4 + 2][row] = wv.z;
            sm.st.Ws[q * 4 + 3][row] = wv.w;
            const float4 nv = *(const float4*)&Wn[(size_t)row * D + k0 + q * 4];
            sm.st.Ws[q * 4 + 0][NEXP + row] = nv.x;
            sm.st.Ws[q * 4 + 1][NEXP + row] = nv.y;
            sm.st.Ws[q * 4 + 2][NEXP + row] = nv.z;
            sm.st.Ws[q * 4 + 3][NEXP + row] = nv.w;
        }
        __syncthreads();
#pragma unroll 4
        for (int kk = 0; kk < BK; ++kk) {
            const float4 xa = *(const float4*)&sm.st.Xs[kk][r0];
            const float4 xb = *(const float4*)&sm.st.Xs[kk][r0 + 4];
            const float4 wv = *(const float4*)&sm.st.Ws[kk][c0];
            const float xs[8] = {xa.x, xa.y, xa.z, xa.w, xb.x, xb.y, xb.z, xb.w};
            const float ws[4] = {wv.x, wv.y, wv.z, wv.w};
#pragma unroll
            for (int i = 0; i < 8; ++i)
#pragma unroll
                for (int j = 0; j < 4; ++j)
                    acc[i][j] = fmaf(xs[i], ws[j], acc[i][j]);
        }
        __syncthreads();
    }
    {
        const float4 bv = (c0 < NEXP) ? *(const float4*)&br[c0]
                                      : *(const float4*)&bn[c0 - NEXP];
#pragma unroll
        for (int i = 0; i < 8; ++i) {
            float4 o;
            o.x = acc[i][0] + bv.x;
            o.y = acc[i][1] + bv.y;
            o.z = acc[i][2] + bv.z;
            o.w = acc[i][3] + bv.w;
            *(float4*)&sm.L[r0 + i][c0] = o;
        }
    }
    __syncthreads();
#pragma unroll
    for (int t = 0; t < 4; ++t) {
        const int f   = tid * 4 + t * 1024;
        const int row = f >> 6;
        const int e0  = f & 63;
        const float4 ev = *(const float4*)&eps[(size_t)(rowbase + row) * NEXP + e0];
        const float evs[4] = {ev.x, ev.y, ev.z, ev.w};
#pragma unroll
        for (int j = 0; j < 4; ++j) {
            const float lg = sm.L[row][e0 + j];
            const float nz = sm.L[row][NEXP + e0 + j];
            sm.L[row][e0 + j] = fmaf(evs[j], softplus_f(nz), lg);
        }
    }
    __syncthreads();
    if (tid < TM) {
        const int r = tid;
        float v1 = -INFINITY, v2 = -INFINITY;
        int i1 = 0, i2 = 0;
#pragma unroll 8
        for (int e = 0; e < NEXP; ++e) {
            const float v = sm.L[r][e];
            if (v > v1) { v2 = v1; i2 = i1; v1 = v; i1 = e; }
            else if (v > v2) { v2 = v; i2 = e; }
        }
        const float z = expf(v2 - v1);
        const float s = 1.0f + z;
        p1s[r] = 1.0f / s;
        p2s[r] = z / s;
        i1s[r] = i1;
        i2s[r] = i2;
        float* oidx = out + (size_t)N * NEXP + (size_t)(rowbase + r) * 2;
        oidx[0] = (float)i1;
        oidx[1] = (float)i2;
    }
    __syncthreads();
    {
        const int r = tid >> 2;
        const int g = tid & 3;
        const float pa = p1s[r], pb = p2s[r];
        const int i1 = i1s[r], i2 = i2s[r];
        float* orow = out + (size_t)(rowbase + r) * NEXP;
#pragma unroll
        for (int t = 0; t < 4; ++t) {
            const int e0 = g * 16 + t * 4;
            float4 o;
            o.x = (e0 + 0 == i1) ? pa : ((e0 + 0 == i2) ? pb : 0.0f);
            o.y = (e0 + 1 == i1) ? pa : ((e0 + 1 == i2) ? pb : 0.0f);
            o.z = (e0 + 2 == i1) ? pa : ((e0 + 2 == i2) ? pb : 0.0f);
            o.w = (e0 + 3 == i1) ? pa : ((e0 + 3 == i2) ? pb : 0.0f);
            *(float4*)&orow[e0] = o;
        }
    }
}

extern "C" void kernel_launch(void* const* d_in, const int* in_sizes, int n_in,
                              void* d_out, int out_size, void* d_ws, size_t ws_size,
                              hipStream_t stream) {
    const float* x   = (const float*)d_in[0];
    const float* Wr  = (const float*)d_in[1];
    const float* br  = (const float*)d_in[2];
    const float* Wn  = (const float*)d_in[3];
    const float* bn  = (const float*)d_in[4];
    const float* eps = (const float*)d_in[5];
    float* out = (float*)d_out;

    const int E = in_sizes[2];
    const int D = in_sizes[1] / E;
    const int N = in_sizes[0] / D;

    const size_t ws_needed = (size_t)128 * D * 2 * sizeof(f16);
    const bool fast = (E == 64) && (D == 2048) && (N % TMR == 0) && (ws_size >= ws_needed);

    if (fast) {
        const int pre_threads = 128 * (D / 8);
        wsplit_kernel<<<(pre_threads + 255) / 256, 256, 0, stream>>>(Wr, Wn, (f16*)d_ws, D);
        router_mfma_kernel<<<N / TMR, 256, 0, stream>>>(x, (const f16*)d_ws, br, bn, eps, out, N, D);
    } else {
        noisy_topk_router_kernel<<<N / TM, 256, 0, stream>>>(x, Wr, br, Wn, bn, eps, out, N, D);
    }
}

// Round 5
// 408.385 us; speedup vs baseline: 1.2956x; 1.0614x over previous
//
#include <hip/hip_runtime.h>
#include <math.h>

typedef _Float16 f16;
typedef __attribute__((ext_vector_type(8))) _Float16 half8;
typedef __attribute__((ext_vector_type(4))) float f32x4;

#define NEXP 64
#define TM 64
#define L_STRIDE 132

__device__ __forceinline__ float softplus_f(float x) {
    return fmaxf(x, 0.0f) + log1pf(expf(-fabsf(x)));
}

__device__ __forceinline__ void lds_dma16(const void* g, void* l) {
    __builtin_amdgcn_global_load_lds(
        (const __attribute__((address_space(1))) unsigned int*)g,
        (__attribute__((address_space(3))) unsigned int*)l, 16, 0, 0);
}

__device__ __forceinline__ void cvt_split(const float4 a, const float4 b,
                                          half8& hv, half8& lv) {
    const float vv[8] = {a.x, a.y, a.z, a.w, b.x, b.y, b.z, b.w};
#pragma unroll
    for (int j = 0; j < 8; ++j) {
        const f16 h = (f16)vv[j];
        hv[j] = h;
        lv[j] = (f16)((vv[j] - (float)h) * 4096.0f);
    }
}

// ---------------- pre-kernel: split W (route|noise) into f16 hi/lo planes ----
// ws layout (f16 units): [kc][plane(2)][q(4)][col(128)][8]   (16 KB per kc)
__global__ void wsplit_kernel(const float* __restrict__ Wr,
                              const float* __restrict__ Wn,
                              f16* __restrict__ ws, int D) {
    const int per_col = D >> 3;
    const int t = blockIdx.x * blockDim.x + threadIdx.x;
    const int col = t / per_col;
    const int k0  = (t - col * per_col) * 8;
    if (col >= 128) return;
    const float* src = (col < NEXP) ? &Wr[(size_t)col * D] : &Wn[(size_t)(col - NEXP) * D];
    const float4 v0 = *(const float4*)&src[k0];
    const float4 v1 = *(const float4*)&src[k0 + 4];
    half8 hi, lo;
    cvt_split(v0, v1, hi, lo);
    const int kc = k0 >> 5, q = (k0 >> 3) & 3;
    const size_t base = (size_t)kc * 8192 + (size_t)q * 1024 + (size_t)col * 8;
    *(half8*)&ws[base]        = hi;
    *(half8*)&ws[base + 4096] = lo;
}

// ---------------- main kernel: TRIPLE-buffered deep pipeline -----------------
// The measured invariant (rounds 0/2/4): ~6100 cyc per K-chunk regardless of
// sync flavor / occupancy / work-per-block. Cause: double buffering gives the
// B-DMA only ONE body of latency cover (issued top of body kc, required done
// at end of body kc). Fix: 3 buffers, prefetch distance 2 -> each DMA has ~2
// full bodies in flight before the counted wait retires it. Queue accounting
// (in-order VMEM retirement; groups pinned by sched_barrier(0)):
//   body kc issues: [DMA(kc+2) x4, xload(kc+3) x2]
//   end of body kc outstanding: [DMA(kc+1)4, x(kc+2)2, DMA(kc+2)4, x(kc+3)2]
//   -> vmcnt(8) retires exactly DMA(kc+1) (2 bodies old). Never drains.
__global__ __launch_bounds__(256, 2)
void router_mfma_kernel(const float* __restrict__ x,
                        const f16* __restrict__ wsW,
                        const float* __restrict__ br,
                        const float* __restrict__ bn,
                        const float* __restrict__ eps,
                        float* __restrict__ out,
                        int N, int D) {
    // st.B[b]: [plane][q][col][8] f16 = 16 KB/buf; st.A[b]: [plane][q][row][8] = 8 KB/buf
    __shared__ union alignas(16) {
        struct { f16 B[3][8192]; f16 A[3][4096]; } st;    // 72 KB
        struct {
            float L[TM][L_STRIDE];                        // 33.8 KB
            float p1[TM], p2[TM];
            int   i1[TM], i2[TM];
        } ep;
    } sm;

    const int tid  = threadIdx.x;
    const int lane = tid & 63;
    const int w    = tid >> 6;
    const int rowbase = blockIdx.x * TM;
    const int wr = w & 1, wc = w >> 1;     // wave tile: 32 rows x 64 cols
    const int quad = lane >> 4;
    const int l16  = lane & 15;

    f32x4 accM[2][4], accC[2][4];
#pragma unroll
    for (int i = 0; i < 2; ++i)
#pragma unroll
        for (int j = 0; j < 4; ++j) {
            accM[i][j] = (f32x4){0.f, 0.f, 0.f, 0.f};
            accC[i][j] = (f32x4){0.f, 0.f, 0.f, 0.f};
        }

    // x staging mapping: row sr (0..63), k-group sq (0..3) -> 32B per thread/chunk
    const int sr = tid >> 2;
    const int sq = tid & 3;
    const float* xrow = &x[(size_t)(rowbase + sr) * D + sq * 8];
    const int nkc = D >> 5;   // 64 (even; host guards D==2048)

    // Two x register sets: E consumed by even bodies (odd chunks), O by odd.
    float4 xe0, xe1, xo0, xo1;

    // ---- prologue: x(0..2) loads first (oldest), then DMA B(0),B(1);
    //      cvt+write A(0); retire {x0,x1,x2,DMA(0)} -> keep DMA(1) in flight.
    {
        const float4 t0 = *(const float4*)&xrow[0];
        const float4 t1 = *(const float4*)&xrow[4];
        xe0 = *(const float4*)&xrow[32];   // chunk 1
        xe1 = *(const float4*)&xrow[36];
        xo0 = *(const float4*)&xrow[64];   // chunk 2
        xo1 = *(const float4*)&xrow[68];
        __builtin_amdgcn_sched_barrier(0);
        const char* g0 = (const char*)wsW + w * 4096 + lane * 16;
        char* d0 = (char*)&sm.st.B[0][0] + w * 4096;
#pragma unroll
        for (int i = 0; i < 4; ++i) lds_dma16(g0 + i * 1024, d0 + i * 1024);
        const char* g1 = (const char*)wsW + 16384 + w * 4096 + lane * 16;
        char* d1 = (char*)&sm.st.B[1][0] + w * 4096;
#pragma unroll
        for (int i = 0; i < 4; ++i) lds_dma16(g1 + i * 1024, d1 + i * 1024);
        __builtin_amdgcn_sched_barrier(0);
        half8 hv, lv;
        cvt_split(t0, t1, hv, lv);          // implicit wait retires x(0)
        *(half8*)&sm.st.A[0][sq * 512 + sr * 8]        = hv;
        *(half8*)&sm.st.A[0][2048 + sq * 512 + sr * 8] = lv;
        asm volatile("s_waitcnt vmcnt(4) lgkmcnt(0)" : : : "memory");
        __builtin_amdgcn_s_barrier();
        __builtin_amdgcn_sched_barrier(0);
    }

    // Rotating buffer indices (uniform scalars): compute bC=kc%3,
    // A-stage bA=(kc+1)%3, B-stage bS=(kc+2)%3.
    int bC = 0, bA = 1, bS = 2;

#define KBODY(KC, X0, X1)                                                      \
    {                                                                          \
        /* stage A(KC+1) from regs loaded 2 bodies ago */                      \
        if ((KC) + 1 < nkc) {                                                  \
            half8 hv, lv;                                                      \
            cvt_split(X0, X1, hv, lv);                                         \
            *(half8*)&sm.st.A[bA][sq * 512 + sr * 8]        = hv;              \
            *(half8*)&sm.st.A[bA][2048 + sq * 512 + sr * 8] = lv;              \
        }                                                                      \
        __builtin_amdgcn_sched_barrier(0);                                     \
        /* DMA B(KC+2) -> 2 bodies of cover before its consumer wait */        \
        if ((KC) + 2 < nkc) {                                                  \
            const char* gsrc = (const char*)wsW + (size_t)((KC) + 2) * 16384   \
                               + w * 4096 + lane * 16;                         \
            char* ldst = (char*)&sm.st.B[bS][0] + w * 4096;                    \
            lds_dma16(gsrc,        ldst);                                      \
            lds_dma16(gsrc + 1024, ldst + 1024);                               \
            lds_dma16(gsrc + 2048, ldst + 2048);                               \
            lds_dma16(gsrc + 3072, ldst + 3072);                               \
        }                                                                      \
        __builtin_amdgcn_sched_barrier(0);                                     \
        /* x regs for chunk KC+3 (consumed 2 bodies from now) */               \
        if ((KC) + 3 < nkc) {                                                  \
            X0 = *(const float4*)&xrow[((KC) + 3) * 32];                       \
            X1 = *(const float4*)&xrow[((KC) + 3) * 32 + 4];                   \
        }                                                                      \
        __builtin_amdgcn_sched_barrier(0);                                     \
        half8 ah[2], al[2], bh[4], bl[4];                                      \
        _Pragma("unroll")                                                      \
        for (int rt = 0; rt < 2; ++rt) {                                       \
            const int r = (wr * 32 + rt * 16 + l16) * 8;                       \
            ah[rt] = *(const half8*)&sm.st.A[bC][quad * 512 + r];              \
            al[rt] = *(const half8*)&sm.st.A[bC][2048 + quad * 512 + r];       \
        }                                                                      \
        _Pragma("unroll")                                                      \
        for (int ct = 0; ct < 4; ++ct) {                                       \
            const int c = (wc * 64 + ct * 16 + l16) * 8;                       \
            bh[ct] = *(const half8*)&sm.st.B[bC][quad * 1024 + c];             \
            bl[ct] = *(const half8*)&sm.st.B[bC][4096 + quad * 1024 + c];      \
        }                                                                      \
        _Pragma("unroll")                                                      \
        for (int rt = 0; rt < 2; ++rt)                                         \
            _Pragma("unroll")                                                  \
            for (int ct = 0; ct < 4; ++ct) {                                   \
                accM[rt][ct] = __builtin_amdgcn_mfma_f32_16x16x32_f16(         \
                    ah[rt], bh[ct], accM[rt][ct], 0, 0, 0);                    \
                accC[rt][ct] = __builtin_amdgcn_mfma_f32_16x16x32_f16(         \
                    al[rt], bh[ct], accC[rt][ct], 0, 0, 0);                    \
                accC[rt][ct] = __builtin_amdgcn_mfma_f32_16x16x32_f16(         \
                    ah[rt], bl[ct], accC[rt][ct], 0, 0, 0);                    \
            }                                                                  \
        /* retire DMA(KC+1) only: issued 2 bodies ago. Tail bodies drain. */   \
        if ((KC) == 0)                                                         \
            asm volatile("s_waitcnt vmcnt(6) lgkmcnt(0)" : : : "memory");      \
        else if ((KC) + 4 < nkc)                                               \
            asm volatile("s_waitcnt vmcnt(8) lgkmcnt(0)" : : : "memory");      \
        else                                                                   \
            asm volatile("s_waitcnt vmcnt(0) lgkmcnt(0)" : : : "memory");      \
        __builtin_amdgcn_s_barrier();                                          \
        __builtin_amdgcn_sched_barrier(0);                                     \
        { const int t_ = bC; bC = bA; bA = bS; bS = t_; }                      \
    }

    for (int kc = 0; kc < nkc; kc += 2) {
        KBODY(kc,     xe0, xe1)
        KBODY(kc + 1, xo0, xo1)
    }
#undef KBODY

    // ---- combine accs + bias -> logits in LDS (C/D: col=lane&15, row=quad*4+rg)
    {
        const float* bias = wc ? bn : br;   // wave-uniform plane select
#pragma unroll
        for (int rt = 0; rt < 2; ++rt)
#pragma unroll
            for (int ct = 0; ct < 4; ++ct) {
                const int row = wr * 32 + rt * 16 + quad * 4;
                const int col = wc * 64 + ct * 16 + l16;
                const float bcol = bias[ct * 16 + l16];
#pragma unroll
                for (int rg = 0; rg < 4; ++rg)
                    sm.ep.L[row + rg][col] =
                        accM[rt][ct][rg] + accC[rt][ct][rg] * (1.0f / 4096.0f) + bcol;
            }
    }
    __syncthreads();

    // ---- noisy logits in-place over cols 0..63
#pragma unroll
    for (int t = 0; t < 4; ++t) {
        const int f   = tid * 4 + t * 1024;
        const int row = f >> 6;
        const int e0  = f & 63;
        const float4 ev = *(const float4*)&eps[(size_t)(rowbase + row) * NEXP + e0];
        const float evs[4] = {ev.x, ev.y, ev.z, ev.w};
#pragma unroll
        for (int j = 0; j < 4; ++j) {
            const float lg = sm.ep.L[row][e0 + j];
            const float nz = sm.ep.L[row][NEXP + e0 + j];
            sm.ep.L[row][e0 + j] = fmaf(evs[j], softplus_f(nz), lg);
        }
    }
    __syncthreads();

    // ---- per-row top-2 (strict > = first-occurrence tie-break, matches top_k)
    if (tid < TM) {
        const int r = tid;
        float v1t = -INFINITY, v2t = -INFINITY;
        int i1 = 0, i2 = 0;
#pragma unroll 8
        for (int e = 0; e < NEXP; ++e) {
            const float v = sm.ep.L[r][e];
            if (v > v1t) { v2t = v1t; i2 = i1; v1t = v; i1 = e; }
            else if (v > v2t) { v2t = v; i2 = e; }
        }
        const float z = expf(v2t - v1t);
        const float s = 1.0f + z;
        sm.ep.p1[r] = 1.0f / s;
        sm.ep.p2[r] = z / s;
        sm.ep.i1[r] = i1;
        sm.ep.i2[r] = i2;
        float* oidx = out + (size_t)N * NEXP + (size_t)(rowbase + r) * 2;
        oidx[0] = (float)i1;
        oidx[1] = (float)i2;
    }
    __syncthreads();

    // ---- sparse-softmax rows, coalesced
    {
        const int r = tid >> 2;
        const int g = tid & 3;
        const float pa = sm.ep.p1[r], pb = sm.ep.p2[r];
        const int i1 = sm.ep.i1[r], i2 = sm.ep.i2[r];
        float* orow = out + (size_t)(rowbase + r) * NEXP;
#pragma unroll
        for (int t = 0; t < 4; ++t) {
            const int e0 = g * 16 + t * 4;
            float4 o;
            o.x = (e0 + 0 == i1) ? pa : ((e0 + 0 == i2) ? pb : 0.0f);
            o.y = (e0 + 1 == i1) ? pa : ((e0 + 1 == i2) ? pb : 0.0f);
            o.z = (e0 + 2 == i1) ? pa : ((e0 + 2 == i2) ? pb : 0.0f);
            o.w = (e0 + 3 == i1) ? pa : ((e0 + 3 == i2) ? pb : 0.0f);
            *(float4*)&orow[e0] = o;
        }
    }
}

// ---------------- fallback: verified fp32 kernel from R1 ---------------------
#define BK 32
#define XS_STRIDE (TM + 4)
#define WS_STRIDE (128 + 4)

__global__ __launch_bounds__(256, 2)
void noisy_topk_router_kernel(const float* __restrict__ x,
                              const float* __restrict__ Wr,
                              const float* __restrict__ br,
                              const float* __restrict__ Wn,
                              const float* __restrict__ bn,
                              const float* __restrict__ eps,
                              float* __restrict__ out,
                              int N, int D) {
    __shared__ union alignas(16) {
        struct {
            float Xs[BK][XS_STRIDE];
            float Ws[BK][WS_STRIDE];
        } st;
        float L[TM][L_STRIDE];
    } sm;
    __shared__ float p1s[TM], p2s[TM];
    __shared__ int   i1s[TM], i2s[TM];

    const int tid = threadIdx.x;
    const int rowbase = blockIdx.x * TM;
    const int r0 = (tid >> 5) * 8;
    const int c0 = (tid & 31) * 4;

    float acc[8][4];
#pragma unroll
    for (int i = 0; i < 8; ++i)
#pragma unroll
        for (int j = 0; j < 4; ++j) acc[i][j] = 0.0f;

    const int q  = tid & 7;
    const int rr = tid >> 3;

    for (int k0 = 0; k0 < D; k0 += BK) {
#pragma unroll
        for (int i = 0; i < 2; ++i) {
            const int row = rr + 32 * i;
            const float4 xv = *(const float4*)&x[(size_t)(rowbase + row) * D + k0 + q * 4];
            sm.st.Xs[q * 4 + 0][row] = xv.x;
            sm.st.Xs[q * 4 + 1][row] = xv.y;
            sm.st.Xs[q * 4 + 2][row] = xv.z;
            sm.st.Xs[q * 4 + 3][row] = xv.w;
            const float4 wv = *(const float4*)&Wr[(size_t)row * D + k0 + q * 4];
            sm.st.Ws[q * 4 + 0][row] = wv.x;
            sm.st.Ws[q * 4 + 1][row] = wv.y;
            sm.st.Ws[q * 4 + 2][row] = wv.z;
            sm.st.Ws[q * 4 + 3][row] = wv.w;
            const float4 nv = *(const float4*)&Wn[(size_t)row * D + k0 + q * 4];
            sm.st.Ws[q * 4 + 0][NEXP + row] = nv.x;
            sm.st.Ws[q * 4 + 1][NEXP + row] = nv.y;
            sm.st.Ws[q * 4 + 2][NEXP + row] = nv.z;
            sm.st.Ws[q * 4 + 3][NEXP + row] = nv.w;
        }
        __syncthreads();
#pragma unroll 4
        for (int kk = 0; kk < BK; ++kk) {
            const float4 xa = *(const float4*)&sm.st.Xs[kk][r0];
            const float4 xb = *(const float4*)&sm.st.Xs[kk][r0 + 4];
            const float4 wv = *(const float4*)&sm.st.Ws[kk][c0];
            const float xs[8] = {xa.x, xa.y, xa.z, xa.w, xb.x, xb.y, xb.z, xb.w};
            const float ws[4] = {wv.x, wv.y, wv.z, wv.w};
#pragma unroll
            for (int i = 0; i < 8; ++i)
#pragma unroll
                for (int j = 0; j < 4; ++j)
                    acc[i][j] = fmaf(xs[i], ws[j], acc[i][j]);
        }
        __syncthreads();
    }
    {
        const float4 bv = (c0 < NEXP) ? *(const float4*)&br[c0]
                                      : *(const float4*)&bn[c0 - NEXP];
#pragma unroll
        for (int i = 0; i < 8; ++i) {
            float4 o;
            o.x = acc[i][0] + bv.x;
            o.y = acc[i][1] + bv.y;
            o.z = acc[i][2] + bv.z;
            o.w = acc[i][3] + bv.w;
            *(float4*)&sm.L[r0 + i][c0] = o;
        }
    }
    __syncthreads();
#pragma unroll
    for (int t = 0; t < 4; ++t) {
        const int f   = tid * 4 + t * 1024;
        const int row = f >> 6;
        const int e0  = f & 63;
        const float4 ev = *(const float4*)&eps[(size_t)(rowbase + row) * NEXP + e0];
        const float evs[4] = {ev.x, ev.y, ev.z, ev.w};
#pragma unroll
        for (int j = 0; j < 4; ++j) {
            const float lg = sm.L[row][e0 + j];
            const float nz = sm.L[row][NEXP + e0 + j];
            sm.L[row][e0 + j] = fmaf(evs[j], softplus_f(nz), lg);
        }
    }
    __syncthreads();
    if (tid < TM) {
        const int r = tid;
        float v1 = -INFINITY, v2 = -INFINITY;
        int i1 = 0, i2 = 0;
#pragma unroll 8
        for (int e = 0; e < NEXP; ++e) {
            const float v = sm.L[r][e];
            if (v > v1) { v2 = v1; i2 = i1; v1 = v; i1 = e; }
            else if (v > v2) { v2 = v; i2 = e; }
        }
        const float z = expf(v2 - v1);
        const float s = 1.0f + z;
        p1s[r] = 1.0f / s;
        p2s[r] = z / s;
        i1s[r] = i1;
        i2s[r] = i2;
        float* oidx = out + (size_t)N * NEXP + (size_t)(rowbase + r) * 2;
        oidx[0] = (float)i1;
        oidx[1] = (float)i2;
    }
    __syncthreads();
    {
        const int r = tid >> 2;
        const int g = tid & 3;
        const float pa = p1s[r], pb = p2s[r];
        const int i1 = i1s[r], i2 = i2s[r];
        float* orow = out + (size_t)(rowbase + r) * NEXP;
#pragma unroll
        for (int t = 0; t < 4; ++t) {
            const int e0 = g * 16 + t * 4;
            float4 o;
            o.x = (e0 + 0 == i1) ? pa : ((e0 + 0 == i2) ? pb : 0.0f);
            o.y = (e0 + 1 == i1) ? pa : ((e0 + 1 == i2) ? pb : 0.0f);
            o.z = (e0 + 2 == i1) ? pa : ((e0 + 2 == i2) ? pb : 0.0f);
            o.w = (e0 + 3 == i1) ? pa : ((e0 + 3 == i2) ? pb : 0.0f);
            *(float4*)&orow[e0] = o;
        }
    }
}

extern "C" void kernel_launch(void* const* d_in, const int* in_sizes, int n_in,
                              void* d_out, int out_size, void* d_ws, size_t ws_size,
                              hipStream_t stream) {
    const float* x   = (const float*)d_in[0];
    const float* Wr  = (const float*)d_in[1];
    const float* br  = (const float*)d_in[2];
    const float* Wn  = (const float*)d_in[3];
    const float* bn  = (const float*)d_in[4];
    const float* eps = (const float*)d_in[5];
    float* out = (float*)d_out;

    const int E = in_sizes[2];
    const int D = in_sizes[1] / E;
    const int N = in_sizes[0] / D;

    const size_t ws_needed = (size_t)128 * D * 2 * sizeof(f16);
    const bool fast = (E == 64) && (D == 2048) && (N % TM == 0) && (ws_size >= ws_needed);

    if (fast) {
        const int pre_threads = 128 * (D / 8);
        wsplit_kernel<<<(pre_threads + 255) / 256, 256, 0, stream>>>(Wr, Wn, (f16*)d_ws, D);
        router_mfma_kernel<<<N / TM, 256, 0, stream>>>(x, (const f16*)d_ws, br, bn, eps, out, N, D);
    } else {
        noisy_topk_router_kernel<<<N / TM, 256, 0, stream>>>(x, Wr, br, Wn, bn, eps, out, N, D);
    }
}